// Round 5
// baseline (102.138 us; speedup 1.0000x reference)
//
#include <hip/hip_runtime.h>

// Problem constants (reference: shape (32, 3, 512, 512) float32).
#define HW       (512 * 512)        // 262144 elements per channel plane
#define NPIX     (32 * HW)          // 8,388,608 pixels per tensor
#define NGROUP   (NPIX / 4)         // 2,097,152 float4 pixel-groups
#define NBLOCKS  2048
#define NTHREADS 256
#define TOTAL_T  (NBLOCKS * NTHREADS)   // 524,288 threads; 4 groups/thread
#define SCALE    2097152.0f             // 2^21 fixed-point scale

// s = (max-min)/max on rgb=(x+1)*0.5  ==  (mx-mn)/(mx+1) on raw x, 0 if mx+1==0
__device__ __forceinline__ float sat_raw(float r, float g, float b) {
    float mx = fmaxf(fmaxf(r, g), b);
    float mn = fminf(fminf(r, g), b);
    float vp = mx + 1.0f;
    return (vp > 0.0f) ? ((mx - mn) / vp) : 0.0f;
}

__global__ __launch_bounds__(NTHREADS) void sat_loss_fused(
        const float* __restrict__ gen,
        const float* __restrict__ tgt,
        unsigned long long* __restrict__ acc,   // d_ws[0]
        unsigned int* __restrict__ count,       // d_ws[8]
        float* __restrict__ out) {
    const int tid = blockIdx.x * NTHREADS + threadIdx.x;

    float s = 0.0f;
    #pragma unroll
    for (int k = 0; k < 4; ++k) {
        const int g = tid + k * TOTAL_T;
        const int b = g >> 16;                 // g / 65536 groups-per-batch
        const long r = (long)(g & 65535) << 2;
        const long base = (long)b * (3L * HW) + r;

        const float4 ar = *(const float4*)(gen + base);
        const float4 ag = *(const float4*)(gen + base + HW);
        const float4 ab = *(const float4*)(gen + base + 2L * HW);
        const float4 br = *(const float4*)(tgt + base);
        const float4 bg = *(const float4*)(tgt + base + HW);
        const float4 bb = *(const float4*)(tgt + base + 2L * HW);

        s += fabsf(sat_raw(ar.x, ag.x, ab.x) - sat_raw(br.x, bg.x, bb.x));
        s += fabsf(sat_raw(ar.y, ag.y, ab.y) - sat_raw(br.y, bg.y, bb.y));
        s += fabsf(sat_raw(ar.z, ag.z, ab.z) - sat_raw(br.z, bg.z, bb.z));
        s += fabsf(sat_raw(ar.w, ag.w, ab.w) - sat_raw(br.w, bg.w, bb.w));
    }

    // wave-64 reduce
    #pragma unroll
    for (int off = 32; off > 0; off >>= 1)
        s += __shfl_down(s, off, 64);

    __shared__ float wave_sum[NTHREADS / 64];
    const int lane = threadIdx.x & 63;
    const int wid  = threadIdx.x >> 6;
    if (lane == 0) wave_sum[wid] = s;
    __syncthreads();

    if (threadIdx.x == 0) {
        float bsum = 0.0f;
        #pragma unroll
        for (int i = 0; i < NTHREADS / 64; ++i) bsum += wave_sum[i];

        // Fixed-point device-wide accumulation: integer adds commute exactly
        // -> deterministic regardless of block completion order.
        const unsigned long long fx = (unsigned long long)llrintf(bsum * SCALE);
        atomicAdd(acc, fx);
        __threadfence();                        // release: acc-add before ticket
        const unsigned int prev = atomicAdd(count, 1u);
        if (prev == NBLOCKS - 1) {
            __threadfence();                    // acquire
            const unsigned long long total = atomicAdd(acc, 0ULL); // coherent read
            out[0] = (float)((double)total * (1.0 / (double)SCALE) / (double)NPIX);
        }
    }
}

extern "C" void kernel_launch(void* const* d_in, const int* in_sizes, int n_in,
                              void* d_out, int out_size, void* d_ws, size_t ws_size,
                              hipStream_t stream) {
    const float* gen = (const float*)d_in[0];
    const float* tgt = (const float*)d_in[1];
    float* out = (float*)d_out;
    unsigned long long* acc = (unsigned long long*)d_ws;
    unsigned int* count = (unsigned int*)((char*)d_ws + 8);

    // d_ws is poisoned (0xAA) once before timing and never re-poisoned;
    // zero the 16-byte accumulator block every call (graph-capture legal).
    hipMemsetAsync(d_ws, 0, 16, stream);

    sat_loss_fused<<<NBLOCKS, NTHREADS, 0, stream>>>(gen, tgt, acc, count, out);
}

// Round 6
// 76.070 us; speedup vs baseline: 1.3427x; 1.3427x over previous
//
#include <hip/hip_runtime.h>

// Problem constants (reference: shape (32, 3, 512, 512) float32).
#define HW       (512 * 512)        // 262144 elements per channel plane
#define NPIX     (32 * HW)          // 8,388,608 pixels per tensor
#define NGROUP   (NPIX / 4)         // 2,097,152 float4 pixel-groups
#define NBLOCKS  2048
#define NTHREADS 256
#define SCALE    2097152.0f         // 2^21 fixed-point scale

// s = (max-min)/max on rgb=(x+1)*0.5  ==  (mx-mn)/(mx+1) on raw x, 0 if mx+1==0
__device__ __forceinline__ float sat_raw(float r, float g, float b) {
    float mx = fmaxf(fmaxf(r, g), b);
    float mn = fminf(fminf(r, g), b);
    float vp = mx + 1.0f;
    return (vp > 0.0f) ? ((mx - mn) / vp) : 0.0f;
}

__global__ __launch_bounds__(NTHREADS) void sat_loss_fused(
        const float* __restrict__ gen,
        const float* __restrict__ tgt,
        unsigned long long* __restrict__ acc,   // d_ws[0]
        unsigned int* __restrict__ count,       // d_ws[8]
        float* __restrict__ out) {
    const int tid = blockIdx.x * NTHREADS + threadIdx.x;
    const int stride = NBLOCKS * NTHREADS;

    // Round-1 hot loop (best measured codegen) — unchanged.
    float s = 0.0f;
    for (int g = tid; g < NGROUP; g += stride) {
        const int b = g >> 16;                 // g / 65536 groups-per-batch
        const long r = (long)(g & 65535) << 2;
        const long base = (long)b * (3L * HW) + r;

        const float4 ar = *(const float4*)(gen + base);
        const float4 ag = *(const float4*)(gen + base + HW);
        const float4 ab = *(const float4*)(gen + base + 2L * HW);
        const float4 br = *(const float4*)(tgt + base);
        const float4 bg = *(const float4*)(tgt + base + HW);
        const float4 bb = *(const float4*)(tgt + base + 2L * HW);

        s += fabsf(sat_raw(ar.x, ag.x, ab.x) - sat_raw(br.x, bg.x, bb.x));
        s += fabsf(sat_raw(ar.y, ag.y, ab.y) - sat_raw(br.y, bg.y, bb.y));
        s += fabsf(sat_raw(ar.z, ag.z, ab.z) - sat_raw(br.z, bg.z, bb.z));
        s += fabsf(sat_raw(ar.w, ag.w, ab.w) - sat_raw(br.w, bg.w, bb.w));
    }

    // wave-64 reduce
    #pragma unroll
    for (int off = 32; off > 0; off >>= 1)
        s += __shfl_down(s, off, 64);

    __shared__ float wave_sum[NTHREADS / 64];
    const int lane = threadIdx.x & 63;
    const int wid  = threadIdx.x >> 6;
    if (lane == 0) wave_sum[wid] = s;
    __syncthreads();

    if (threadIdx.x == 0) {
        float bsum = 0.0f;
        #pragma unroll
        for (int i = 0; i < NTHREADS / 64; ++i) bsum += wave_sum[i];

        // Cross-block communication ONLY via device-scope atomics (coherent
        // point) — NO __threadfence(): round-5 showed the fence's L2
        // writeback/invalidate collapses streaming BW 2.4x.
        const unsigned long long fx = (unsigned long long)llrintf(bsum * SCALE);
        unsigned long long old = atomicAdd(acc, fx);     // returning form
        asm volatile("" : : "v"(old));                   // keep sc0 (return) live
        asm volatile("s_waitcnt vmcnt(0)" ::: "memory"); // acc-add complete at
                                                         // coherent point first
        const unsigned int prev = atomicAdd(count, 1u);  // then take ticket
        if (prev == NBLOCKS - 1) {
            // All 2048 acc-adds completed before their tickets -> total is final.
            const unsigned long long total = atomicAdd(acc, 0ULL);
            out[0] = (float)((double)total * (1.0 / (double)SCALE) / (double)NPIX);
        }
    }
}

extern "C" void kernel_launch(void* const* d_in, const int* in_sizes, int n_in,
                              void* d_out, int out_size, void* d_ws, size_t ws_size,
                              hipStream_t stream) {
    const float* gen = (const float*)d_in[0];
    const float* tgt = (const float*)d_in[1];
    float* out = (float*)d_out;
    unsigned long long* acc = (unsigned long long*)d_ws;
    unsigned int* count = (unsigned int*)((char*)d_ws + 8);

    // d_ws is poisoned (0xAA) once before timing and never re-poisoned;
    // zero the 16-byte accumulator block every call (graph-capture legal).
    hipMemsetAsync(d_ws, 0, 16, stream);

    sat_loss_fused<<<NBLOCKS, NTHREADS, 0, stream>>>(gen, tgt, acc, count, out);
}

// Round 7
// 37.010 us; speedup vs baseline: 2.7597x; 2.0554x over previous
//
#include <hip/hip_runtime.h>

// Problem constants (reference: shape (32, 3, 512, 512) float32).
#define HW      (512 * 512)        // 262144 elements per channel plane
#define NBATCH  32
#define NPIX    (NBATCH * HW)      // 8,388,608 pixels per tensor
#define NGROUP  (NPIX / 4)         // 2,097,152 float4 pixel-groups
#define NBLOCKS 2048
#define NTHREADS 256

// rgb = (x + 1) * 0.5 in [0,1]; S = (max - min) / max, 0 where max == 0
__device__ __forceinline__ float saturation(float x_r, float x_g, float x_b) {
    float r = (x_r + 1.0f) * 0.5f;
    float g = (x_g + 1.0f) * 0.5f;
    float b = (x_b + 1.0f) * 0.5f;
    float v  = fmaxf(fmaxf(r, g), b);
    float mn = fminf(fminf(r, g), b);
    float d  = v - mn;
    return (v > 0.0f) ? (d / v) : 0.0f;
}

// ===== Main kernel: EXACT round-1 code (best measured: 38.9 us) =====
__global__ __launch_bounds__(NTHREADS) void sat_loss_partial(
        const float* __restrict__ gen,
        const float* __restrict__ tgt,
        float* __restrict__ partial) {
    const int tid = blockIdx.x * blockDim.x + threadIdx.x;
    const int stride = gridDim.x * blockDim.x;

    float acc = 0.0f;
    for (int g = tid; g < NGROUP; g += stride) {
        const int b = g >> 16;                 // g / (HW/4), HW/4 == 65536
        const long r = (long)(g & 65535) << 2; // element offset within plane
        const long base = (long)b * (3L * HW) + r;

        const float4 ar = *(const float4*)(gen + base);
        const float4 ag = *(const float4*)(gen + base + HW);
        const float4 ab = *(const float4*)(gen + base + 2L * HW);
        const float4 br = *(const float4*)(tgt + base);
        const float4 bg = *(const float4*)(tgt + base + HW);
        const float4 bb = *(const float4*)(tgt + base + 2L * HW);

        acc += fabsf(saturation(ar.x, ag.x, ab.x) - saturation(br.x, bg.x, bb.x));
        acc += fabsf(saturation(ar.y, ag.y, ab.y) - saturation(br.y, bg.y, bb.y));
        acc += fabsf(saturation(ar.z, ag.z, ab.z) - saturation(br.z, bg.z, bb.z));
        acc += fabsf(saturation(ar.w, ag.w, ab.w) - saturation(br.w, bg.w, bb.w));
    }

    // wave-64 butterfly reduce
    #pragma unroll
    for (int off = 32; off > 0; off >>= 1)
        acc += __shfl_down(acc, off, 64);

    __shared__ float wave_sum[NTHREADS / 64];
    const int lane = threadIdx.x & 63;
    const int wid  = threadIdx.x >> 6;
    if (lane == 0) wave_sum[wid] = acc;
    __syncthreads();

    if (threadIdx.x == 0) {
        float s = 0.0f;
        #pragma unroll
        for (int i = 0; i < NTHREADS / 64; ++i) s += wave_sum[i];
        partial[blockIdx.x] = s;
    }
}

// ===== Finalize: one 64-lane wave, no LDS, no barriers =====
// 2048 partials = 512 float4; each lane loads 8 float4, shuffle-tree reduces.
__global__ __launch_bounds__(64) void sat_loss_finalize(
        const float* __restrict__ partial,
        float* __restrict__ out) {
    const int lane = threadIdx.x;   // 0..63
    float acc = 0.0f;
    #pragma unroll
    for (int i = 0; i < 8; ++i) {
        const float4 p = *(const float4*)(partial + ((i * 64 + lane) << 2));
        acc += (p.x + p.y) + (p.z + p.w);
    }
    #pragma unroll
    for (int off = 32; off > 0; off >>= 1)
        acc += __shfl_down(acc, off, 64);
    if (lane == 0)
        out[0] = acc * (1.0f / (float)NPIX);   // WEIGHT == 1.0
}

extern "C" void kernel_launch(void* const* d_in, const int* in_sizes, int n_in,
                              void* d_out, int out_size, void* d_ws, size_t ws_size,
                              hipStream_t stream) {
    const float* gen = (const float*)d_in[0];
    const float* tgt = (const float*)d_in[1];
    float* out = (float*)d_out;
    float* partial = (float*)d_ws;   // NBLOCKS floats = 8 KiB of scratch

    sat_loss_partial<<<NBLOCKS, NTHREADS, 0, stream>>>(gen, tgt, partial);
    sat_loss_finalize<<<1, 64, 0, stream>>>(partial, out);
}